// Round 8
// baseline (1322.245 us; speedup 1.0000x reference)
//
#include <hip/hip_runtime.h>

typedef _Float16 half8 __attribute__((ext_vector_type(8)));
typedef _Float16 half4 __attribute__((ext_vector_type(4)));
typedef _Float16 half2v __attribute__((ext_vector_type(2)));
typedef float f32x4 __attribute__((ext_vector_type(4)));

#define TSIZE (1 << 19)
#define TMASK (TSIZE - 1)

// floor(32 * 1.3819^l) for l=0..15; every value >=0.03 from an integer.
__constant__ int c_res[16] = {32, 44, 61, 84, 116, 161, 222, 307,
                              425, 588, 812, 1123, 1551, 2144, 2963, 4095};

// Fused f32->f16 weight conversion. Segments: W1 32768, W2 262144, W3 196608 elems.
__global__ void hg_cvt_all(const float* __restrict__ W1, const float* __restrict__ W2,
                           const float* __restrict__ W3, _Float16* __restrict__ d) {
  int g = blockIdx.x * blockDim.x + threadIdx.x;  // 122880 groups of 4
  int i = g * 4;
  const float* s;
  if (i < 32768) s = W1 + i;
  else if (i < 32768 + 262144) s = W2 + (i - 32768);
  else s = W3 + (i - 32768 - 262144);
  float4 v = *(const float4*)s;
  half4 h = {(_Float16)v.x, (_Float16)v.y, (_Float16)v.z, (_Float16)v.w};
  *(half4*)(d + i) = h;
}

// Final-layer sin: deg-9 Taylor (|err|<3e-8) on |x|<=1 (clamp = identity there);
// rare outliers take the precise clamped sinf path.
__device__ __forceinline__ float sin_act_precise(float x) {
  if (__builtin_expect(fabsf(x) > 1.0f, 0))
    return sinf(fminf(fmaxf(x, -25.133f), 25.133f));
  float x2 = x * x;
  float p = 2.75573192e-6f;
  p = fmaf(p, x2, -1.98412698e-4f);
  p = fmaf(p, x2, 8.33333333e-3f);
  p = fmaf(p, x2, -1.66666667e-1f);
  return fmaf(p * x2, x, x);
}

// Intermediate-layer sin: clamp + __sinf (v_sin). Abs err <=~1e-5, far below the
// 3e-4 f16-storage rounding already applied to intermediates; ~3 VALU ops.
__device__ __forceinline__ float sin_act_fast(float x) {
  return __sinf(fminf(fmaxf(x, -25.133f), 25.133f));
}

// LDS layout (PADDED rows, no XOR): X [128 pts][144 B] at 0 (18432 B),
// S [128 pts][1040 B] at 18432 (133120 B). Total 151552 B -> 1 block/CU.
// Row strides 144,1040 ≡ 16 (mod 128): 16 consecutive rows hit 8 distinct 16B
// slots pairwise (2-way = free, m136); addresses are base + k*64 immediates.
#define XROW 144
#define SBASE 18432
#define SROW 1040
#define LD_X(m, k) (*(const half8*)(&smem[(m) * XROW + (k) * 2]))
#define LD_S(m, k) (*(const half8*)(&smem[SBASE + (m) * SROW + (k) * 2]))
#define ST_S8(m, n, v) \
  do { *(half4*)(&smem[SBASE + (m) * SROW + (n) * 2]) = (v); } while (0)

#define MFMA16 __builtin_amdgcn_mfma_f32_16x16x32_f16

__global__ void __launch_bounds__(1024, 4)  // cap 128 regs/wave (acc->AGPR + 64 arch, R5-proven)
hg_fused(const int* __restrict__ ybuf, const int* __restrict__ xbuf,
         const float* __restrict__ cam, const float* __restrict__ table,
         const _Float16* __restrict__ W1h, const float* __restrict__ b1,
         const _Float16* __restrict__ W2h, const float* __restrict__ b2,
         const _Float16* __restrict__ W3h, const float* __restrict__ b3,
         float* __restrict__ out) {
  __shared__ __align__(16) unsigned char smem[151552];
  const int t = threadIdx.x;
  const int lane = t & 63;
  const int wid = t >> 6;     // 16 waves: 2 row-halves x 8 col-groups
  const int l15 = lane & 15;
  const int lhi = lane >> 4;
  const int rowh = wid & 1;
  const int colg = wid >> 1;
  const int mrow0 = rowh * 64;        // this wave's 64-point half
  const int pbase = blockIdx.x << 7;  // 128 points per block
  const f32x4 vzero = {0.f, 0.f, 0.f, 0.f};

  // ---------------- hashgrid encode -> X_lds[128][64] f16 ----------------
  {
    const int sub = t & 15;  // level index; also cam pair index
    const int res = c_res[sub];
    const float rf = (float)res;
    const unsigned strd = (unsigned)(res + 1);
    const bool dense = (res <= 723);  // (res+1)^2 <= 2^19
    const float* tb = table + ((size_t)sub * TSIZE) * 2;
    const float2 cf = ((const float2*)cam)[sub];
    const half2v hc = {(_Float16)cf.x, (_Float16)cf.y};
#pragma unroll
    for (int hh = 0; hh < 2; ++hh) {
      const int m = (t >> 4) + hh * 64;  // local point 0..127
      const int p = pbase + m;
      const float u = (float)xbuf[p] / 511.0f;
      const float v = (float)ybuf[p] / 511.0f;
      const float px = u * rf, py = v * rf;
      int p0x = (int)floorf(px); p0x = p0x < 0 ? 0 : (p0x > res - 1 ? res - 1 : p0x);
      int p0y = (int)floorf(py); p0y = p0y < 0 ? 0 : (p0y > res - 1 ? res - 1 : p0y);
      const float fx = px - (float)p0x, fy = py - (float)p0y;
      const float w00 = (1.f - fx) * (1.f - fy), w10 = fx * (1.f - fy);
      const float w01 = (1.f - fx) * fy, w11 = fx * fy;
      float c0 = 0.f, c1 = 0.f;
#pragma unroll
      for (int c = 0; c < 4; ++c) {
        const unsigned cx = (unsigned)(p0x + (c & 1));
        const unsigned cy = (unsigned)(p0y + (c >> 1));
        const unsigned idx = dense ? (cx + cy * strd)
                                   : ((cx ^ (cy * 2654435761u)) & TMASK);
        const float2 f = *(const float2*)(tb + (size_t)idx * 2);
        const float w = (c == 0) ? w00 : (c == 1) ? w10 : (c == 2) ? w01 : w11;
        c0 = fmaf(w, f.x, c0);
        c1 = fmaf(w, f.y, c1);
      }
      half2v hf = {(_Float16)c0, (_Float16)c1};
      *(half2v*)(&smem[m * XROW + 4 * sub]) = hf;
      *(half2v*)(&smem[m * XROW + 64 + 4 * sub]) = hc;
    }
  }
  __syncthreads();

  // ---------------- L1: sin(X @ W1^T + b1) -> S[128,512] ----------------
  // Swapped operands: mfma(A=W_frag, B=X_frag) => C[row=n][col=point];
  // thread holds 4 consecutive n for one point -> packed 8B LDS stores.
  {
    const int n0 = colg << 6;  // 64 cols per wave
    f32x4 acc[4][4];
#pragma unroll
    for (int i = 0; i < 4; ++i)
#pragma unroll
      for (int j = 0; j < 4; ++j) acc[i][j] = vzero;
#pragma unroll
    for (int ks = 0; ks < 2; ++ks) {
      const int kk = ks * 32 + lhi * 8;
      half8 bw[4];
#pragma unroll
      for (int nf = 0; nf < 4; ++nf)
        bw[nf] = *(const half8*)(W1h + (n0 + nf * 16 + l15) * 64 + kk);
      half8 ax[4];
#pragma unroll
      for (int mf = 0; mf < 4; ++mf) ax[mf] = LD_X(mrow0 + mf * 16 + l15, kk);
#pragma unroll
      for (int mf = 0; mf < 4; ++mf)
#pragma unroll
        for (int nf = 0; nf < 4; ++nf)
          acc[mf][nf] = MFMA16(bw[nf], ax[mf], acc[mf][nf], 0, 0, 0);
    }
    // X and S are disjoint buffers: no barrier needed before these stores
#pragma unroll
    for (int nf = 0; nf < 4; ++nf) {
      const int nb = n0 + nf * 16 + lhi * 4;
      const f32x4 bb = *(const f32x4*)(b1 + nb);
#pragma unroll
      for (int mf = 0; mf < 4; ++mf) {
        half4 pk;
#pragma unroll
        for (int r = 0; r < 4; ++r)
          pk[r] = (_Float16)sin_act_fast(acc[mf][nf][r] + bb[r]);
        ST_S8(mrow0 + mf * 16 + l15, nb, pk);
      }
    }
  }
  __syncthreads();

  // ---------------- L2: sin(S @ W2^T + b2) -> S (in place after barrier) ----
  {
    const int n0 = colg << 6;
    f32x4 acc[4][4];
#pragma unroll
    for (int i = 0; i < 4; ++i)
#pragma unroll
      for (int j = 0; j < 4; ++j) acc[i][j] = vzero;
    // depth-1 rotating W prefetch (R5-proven register shape; unroll 2 only)
    half8 bw[4];
#pragma unroll
    for (int nf = 0; nf < 4; ++nf)
      bw[nf] = *(const half8*)(W2h + (n0 + nf * 16 + l15) * 512 + lhi * 8);
#pragma unroll 2
    for (int ks = 0; ks < 16; ++ks) {
      const int kkn = ((ks + 1) & 15) * 32 + lhi * 8;  // &15: dummy tail stays in-bounds
      half8 nbw[4];
#pragma unroll
      for (int nf = 0; nf < 4; ++nf)
        nbw[nf] = *(const half8*)(W2h + (n0 + nf * 16 + l15) * 512 + kkn);
      const int kk = ks * 32 + lhi * 8;
      half8 ax[4];
#pragma unroll
      for (int mf = 0; mf < 4; ++mf) ax[mf] = LD_S(mrow0 + mf * 16 + l15, kk);
#pragma unroll
      for (int mf = 0; mf < 4; ++mf)
#pragma unroll
        for (int nf = 0; nf < 4; ++nf)
          acc[mf][nf] = MFMA16(bw[nf], ax[mf], acc[mf][nf], 0, 0, 0);
#pragma unroll
      for (int nf = 0; nf < 4; ++nf) bw[nf] = nbw[nf];
    }
    __syncthreads();  // all waves done READING S1 before overwrite
#pragma unroll
    for (int nf = 0; nf < 4; ++nf) {
      const int nb = n0 + nf * 16 + lhi * 4;
      const f32x4 bb = *(const f32x4*)(b2 + nb);
#pragma unroll
      for (int mf = 0; mf < 4; ++mf) {
        half4 pk;
#pragma unroll
        for (int r = 0; r < 4; ++r)
          pk[r] = (_Float16)sin_act_fast(acc[mf][nf][r] + bb[r]);
        ST_S8(mrow0 + mf * 16 + l15, nb, pk);
      }
    }
  }
  __syncthreads();

  // ---------------- L3: sin(S @ W3^T + b3) -> out[128,384] fp32 ----------------
  {
    const int n0 = colg * 48;  // 48 cols per wave
    f32x4 acc[4][3];
#pragma unroll
    for (int i = 0; i < 4; ++i)
#pragma unroll
      for (int j = 0; j < 3; ++j) acc[i][j] = vzero;
    half8 bw[3];
#pragma unroll
    for (int nf = 0; nf < 3; ++nf)
      bw[nf] = *(const half8*)(W3h + (n0 + nf * 16 + l15) * 512 + lhi * 8);
#pragma unroll 2
    for (int ks = 0; ks < 16; ++ks) {
      const int kkn = ((ks + 1) & 15) * 32 + lhi * 8;
      half8 nbw[3];
#pragma unroll
      for (int nf = 0; nf < 3; ++nf)
        nbw[nf] = *(const half8*)(W3h + (n0 + nf * 16 + l15) * 512 + kkn);
      const int kk = ks * 32 + lhi * 8;
      half8 ax[4];
#pragma unroll
      for (int mf = 0; mf < 4; ++mf) ax[mf] = LD_S(mrow0 + mf * 16 + l15, kk);
#pragma unroll
      for (int mf = 0; mf < 4; ++mf)
#pragma unroll
        for (int nf = 0; nf < 3; ++nf)
          acc[mf][nf] = MFMA16(bw[nf], ax[mf], acc[mf][nf], 0, 0, 0);
#pragma unroll
      for (int nf = 0; nf < 3; ++nf) bw[nf] = nbw[nf];
    }
#pragma unroll
    for (int nf = 0; nf < 3; ++nf) {
      const int nb = n0 + nf * 16 + lhi * 4;
      const f32x4 bb = *(const f32x4*)(b3 + nb);
#pragma unroll
      for (int mf = 0; mf < 4; ++mf) {
        float4 o;
        float* op = &o.x;
#pragma unroll
        for (int r = 0; r < 4; ++r)
          op[r] = sin_act_precise(acc[mf][nf][r] + bb[r]);
        *(float4*)(out + (size_t)(pbase + mrow0 + mf * 16 + l15) * 384 + nb) = o;
      }
    }
  }
}

extern "C" void kernel_launch(void* const* d_in, const int* in_sizes, int n_in,
                              void* d_out, int out_size, void* d_ws, size_t ws_size,
                              hipStream_t stream) {
  const int* y = (const int*)d_in[0];
  const int* x = (const int*)d_in[1];
  const float* cam = (const float*)d_in[2];
  const float* table = (const float*)d_in[3];
  const float* W1 = (const float*)d_in[4];
  const float* b1 = (const float*)d_in[5];
  const float* W2 = (const float*)d_in[6];
  const float* b2 = (const float*)d_in[7];
  const float* W3 = (const float*)d_in[8];
  const float* b3 = (const float*)d_in[9];
  float* out = (float*)d_out;

  _Float16* Wh = (_Float16*)d_ws;      // W1h | W2h | W3h contiguous, 983040 B
  _Float16* W1h = Wh;                  // 512*64
  _Float16* W2h = W1h + 512 * 64;      // 512*512
  _Float16* W3h = W2h + 512 * 512;     // 384*512

  hg_cvt_all<<<480, 256, 0, stream>>>(W1, W2, W3, Wh);

  const int nblocks = (1 << 19) / 128;  // 4096
  hg_fused<<<nblocks, 1024, 0, stream>>>(y, x, cam, table, W1h, b1, W2h, b2, W3h, b3, out);
}

// Round 9
// 1145.035 us; speedup vs baseline: 1.1548x; 1.1548x over previous
//
#include <hip/hip_runtime.h>

typedef _Float16 half8 __attribute__((ext_vector_type(8)));
typedef _Float16 half4 __attribute__((ext_vector_type(4)));
typedef _Float16 half2v __attribute__((ext_vector_type(2)));
typedef float f32x4 __attribute__((ext_vector_type(4)));

#define TSIZE (1 << 19)
#define TMASK (TSIZE - 1)

// floor(32 * 1.3819^l) for l=0..15; every value >=0.03 from an integer.
__constant__ int c_res[16] = {32, 44, 61, 84, 116, 161, 222, 307,
                              425, 588, 812, 1123, 1551, 2144, 2963, 4095};

// Fused f32->f16 weight conversion. Segments: W1 32768, W2 262144, W3 196608 elems.
__global__ void hg_cvt_all(const float* __restrict__ W1, const float* __restrict__ W2,
                           const float* __restrict__ W3, _Float16* __restrict__ d) {
  int g = blockIdx.x * blockDim.x + threadIdx.x;  // 122880 groups of 4
  int i = g * 4;
  const float* s;
  if (i < 32768) s = W1 + i;
  else if (i < 32768 + 262144) s = W2 + (i - 32768);
  else s = W3 + (i - 32768 - 262144);
  float4 v = *(const float4*)s;
  half4 h = {(_Float16)v.x, (_Float16)v.y, (_Float16)v.z, (_Float16)v.w};
  *(half4*)(d + i) = h;
}

// Final-layer sin: deg-9 Taylor (|err|<3e-8) on |x|<=1 (clamp = identity there);
// rare outliers take the precise clamped sinf path. Output is fp32 -> needs this.
__device__ __forceinline__ float sin_act_precise(float x) {
  if (__builtin_expect(fabsf(x) > 1.0f, 0))
    return sinf(fminf(fmaxf(x, -25.133f), 25.133f));
  float x2 = x * x;
  float p = 2.75573192e-6f;
  p = fmaf(p, x2, -1.98412698e-4f);
  p = fmaf(p, x2, 8.33333333e-3f);
  p = fmaf(p, x2, -1.66666667e-1f);
  return fmaf(p * x2, x, x);
}

// Intermediate-layer sin: clamp + __sinf (v_sin). Abs err ~1e-5 << the 3e-4
// f16-storage rounding already applied to intermediates; ~3 VALU ops.
__device__ __forceinline__ float sin_act_fast(float x) {
  return __sinf(fminf(fmaxf(x, -25.133f), 25.133f));
}

// LDS (PADDED rows, no XOR): X [64 pts][144 B] at 0 (9216 B),
// S [64 pts][1040 B] at 9216 (66560 B). Total 75776 B -> 2 blocks/CU.
// Row strides 144,1040 are odd multiples of 16: consecutive rows map to
// rotating 16B bank slots -> <=2-way conflict on ds_read_b128 (2-way is free,
// m136), and addresses reduce to base + k*64 immediates (no per-iter VALU).
#define XROW 144
#define SBASE 9216
#define SROW 1040
#define LD_X(m, k) (*(const half8*)(&smem[(m) * XROW + (k) * 2]))
#define LD_S(m, k) (*(const half8*)(&smem[SBASE + (m) * SROW + (k) * 2]))
#define ST_S8(m, n, v) \
  do { *(half4*)(&smem[SBASE + (m) * SROW + (n) * 2]) = (v); } while (0)

#define MFMA16 __builtin_amdgcn_mfma_f32_16x16x32_f16

__global__ void __launch_bounds__(512, 4)  // cap 128 regs/wave: 64 AGPR acc + ~50 VGPR, clean
hg_fused(const int* __restrict__ ybuf, const int* __restrict__ xbuf,
         const float* __restrict__ cam, const float* __restrict__ table,
         const _Float16* __restrict__ W1h, const float* __restrict__ b1,
         const _Float16* __restrict__ W2h, const float* __restrict__ b2,
         const _Float16* __restrict__ W3h, const float* __restrict__ b3,
         float* __restrict__ out) {
  __shared__ __align__(16) unsigned char smem[75776];
  const int t = threadIdx.x;
  const int lane = t & 63;
  const int wid = t >> 6;   // 8 waves; wave owns all 64 pts x 64 cols (48 in L3)
  const int l15 = lane & 15;
  const int lhi = lane >> 4;
  const int pbase = blockIdx.x << 6;  // 64 points per block
  const f32x4 vzero = {0.f, 0.f, 0.f, 0.f};

  // ---------------- hashgrid encode -> X_lds[64][64] f16 ----------------
  {
    const int sub = t & 15;  // level index; also cam pair index
    const int res = c_res[sub];
    const float rf = (float)res;
    const unsigned strd = (unsigned)(res + 1);
    const bool dense = (res <= 723);  // (res+1)^2 <= 2^19
    const float* tb = table + ((size_t)sub * TSIZE) * 2;
    const float2 cf = ((const float2*)cam)[sub];
    const half2v hc = {(_Float16)cf.x, (_Float16)cf.y};
#pragma unroll
    for (int hh = 0; hh < 2; ++hh) {
      const int m = (t >> 4) + hh * 32;  // local point 0..63
      const int p = pbase + m;
      const float u = (float)xbuf[p] / 511.0f;
      const float v = (float)ybuf[p] / 511.0f;
      const float px = u * rf, py = v * rf;
      int p0x = (int)floorf(px); p0x = p0x < 0 ? 0 : (p0x > res - 1 ? res - 1 : p0x);
      int p0y = (int)floorf(py); p0y = p0y < 0 ? 0 : (p0y > res - 1 ? res - 1 : p0y);
      const float fx = px - (float)p0x, fy = py - (float)p0y;
      const float w00 = (1.f - fx) * (1.f - fy), w10 = fx * (1.f - fy);
      const float w01 = (1.f - fx) * fy, w11 = fx * fy;
      float c0 = 0.f, c1 = 0.f;
#pragma unroll
      for (int c = 0; c < 4; ++c) {
        const unsigned cx = (unsigned)(p0x + (c & 1));
        const unsigned cy = (unsigned)(p0y + (c >> 1));
        const unsigned idx = dense ? (cx + cy * strd)
                                   : ((cx ^ (cy * 2654435761u)) & TMASK);
        const float2 f = *(const float2*)(tb + (size_t)idx * 2);
        const float w = (c == 0) ? w00 : (c == 1) ? w10 : (c == 2) ? w01 : w11;
        c0 = fmaf(w, f.x, c0);
        c1 = fmaf(w, f.y, c1);
      }
      half2v hf = {(_Float16)c0, (_Float16)c1};
      *(half2v*)(&smem[m * XROW + 4 * sub]) = hf;
      *(half2v*)(&smem[m * XROW + 64 + 4 * sub]) = hc;
    }
  }
  __syncthreads();

  // ---------------- L1: sin(X @ W1^T + b1) -> S[64,512] ----------------
  // Swapped operands: mfma(A=W_frag, B=X_frag) => C[row=n][col=point];
  // thread holds 4 consecutive n for one point -> packed 8B LDS stores.
  {
    const int n0 = wid << 6;  // 64 cols per wave
    f32x4 acc[4][4];
#pragma unroll
    for (int i = 0; i < 4; ++i)
#pragma unroll
      for (int j = 0; j < 4; ++j) acc[i][j] = vzero;
#pragma unroll
    for (int ks = 0; ks < 2; ++ks) {
      const int kk = ks * 32 + lhi * 8;
      half8 bw[4];
#pragma unroll
      for (int nf = 0; nf < 4; ++nf)
        bw[nf] = *(const half8*)(W1h + (n0 + nf * 16 + l15) * 64 + kk);
      half8 ax[4];
#pragma unroll
      for (int mf = 0; mf < 4; ++mf) ax[mf] = LD_X(mf * 16 + l15, kk);
#pragma unroll
      for (int mf = 0; mf < 4; ++mf)
#pragma unroll
        for (int nf = 0; nf < 4; ++nf)
          acc[mf][nf] = MFMA16(bw[nf], ax[mf], acc[mf][nf], 0, 0, 0);
    }
    // X and S are disjoint buffers: no barrier needed before these stores
#pragma unroll
    for (int nf = 0; nf < 4; ++nf) {
      const int nb = n0 + nf * 16 + lhi * 4;
      const f32x4 bb = *(const f32x4*)(b1 + nb);
#pragma unroll
      for (int mf = 0; mf < 4; ++mf) {
        half4 pk;
#pragma unroll
        for (int r = 0; r < 4; ++r)
          pk[r] = (_Float16)sin_act_fast(acc[mf][nf][r] + bb[r]);
        ST_S8(mf * 16 + l15, nb, pk);
      }
    }
  }
  __syncthreads();

  // ---------------- L2: sin(S @ W2^T + b2) -> S (in place after barrier) ----
  {
    const int n0 = wid << 6;
    f32x4 acc[4][4];
#pragma unroll
    for (int i = 0; i < 4; ++i)
#pragma unroll
      for (int j = 0; j < 4; ++j) acc[i][j] = vzero;
    // no manual prefetch rotation: direct loads, compiler schedules (R7/R8
    // spills both traced to hand-rolled prefetch register machinery)
#pragma unroll 2
    for (int ks = 0; ks < 16; ++ks) {
      const int kk = ks * 32 + lhi * 8;
      half8 bw[4];
#pragma unroll
      for (int nf = 0; nf < 4; ++nf)
        bw[nf] = *(const half8*)(W2h + (n0 + nf * 16 + l15) * 512 + kk);
      half8 ax[4];
#pragma unroll
      for (int mf = 0; mf < 4; ++mf) ax[mf] = LD_S(mf * 16 + l15, kk);
#pragma unroll
      for (int mf = 0; mf < 4; ++mf)
#pragma unroll
        for (int nf = 0; nf < 4; ++nf)
          acc[mf][nf] = MFMA16(bw[nf], ax[mf], acc[mf][nf], 0, 0, 0);
    }
    // bias+clamp+sin IN PLACE in acc (zero extra registers) before the
    // barrier — overlaps other waves' K-loop tails; pack+store after.
#pragma unroll
    for (int nf = 0; nf < 4; ++nf) {
      const f32x4 bb = *(const f32x4*)(b2 + (n0 + nf * 16 + lhi * 4));
#pragma unroll
      for (int mf = 0; mf < 4; ++mf)
#pragma unroll
        for (int r = 0; r < 4; ++r)
          acc[mf][nf][r] = sin_act_fast(acc[mf][nf][r] + bb[r]);
    }
    __syncthreads();  // all waves done READING S1 before overwrite
#pragma unroll
    for (int nf = 0; nf < 4; ++nf) {
      const int nb = n0 + nf * 16 + lhi * 4;
#pragma unroll
      for (int mf = 0; mf < 4; ++mf) {
        half4 pk = {(_Float16)acc[mf][nf][0], (_Float16)acc[mf][nf][1],
                    (_Float16)acc[mf][nf][2], (_Float16)acc[mf][nf][3]};
        ST_S8(mf * 16 + l15, nb, pk);
      }
    }
  }
  __syncthreads();

  // ---------------- L3: sin(S @ W3^T + b3) -> out[64,384] fp32 ----------------
  {
    const int n0 = wid * 48;  // 48 cols per wave
    f32x4 acc[4][3];
#pragma unroll
    for (int i = 0; i < 4; ++i)
#pragma unroll
      for (int j = 0; j < 3; ++j) acc[i][j] = vzero;
#pragma unroll 2
    for (int ks = 0; ks < 16; ++ks) {
      const int kk = ks * 32 + lhi * 8;
      half8 bw[3];
#pragma unroll
      for (int nf = 0; nf < 3; ++nf)
        bw[nf] = *(const half8*)(W3h + (n0 + nf * 16 + l15) * 512 + kk);
      half8 ax[4];
#pragma unroll
      for (int mf = 0; mf < 4; ++mf) ax[mf] = LD_S(mf * 16 + l15, kk);
#pragma unroll
      for (int mf = 0; mf < 4; ++mf)
#pragma unroll
        for (int nf = 0; nf < 3; ++nf)
          acc[mf][nf] = MFMA16(bw[nf], ax[mf], acc[mf][nf], 0, 0, 0);
    }
#pragma unroll
    for (int nf = 0; nf < 3; ++nf) {
      const int nb = n0 + nf * 16 + lhi * 4;
      const f32x4 bb = *(const f32x4*)(b3 + nb);
#pragma unroll
      for (int mf = 0; mf < 4; ++mf) {
        float4 o;
        float* op = &o.x;
#pragma unroll
        for (int r = 0; r < 4; ++r)
          op[r] = sin_act_precise(acc[mf][nf][r] + bb[r]);
        *(float4*)(out + (size_t)(pbase + mf * 16 + l15) * 384 + nb) = o;
      }
    }
  }
}

extern "C" void kernel_launch(void* const* d_in, const int* in_sizes, int n_in,
                              void* d_out, int out_size, void* d_ws, size_t ws_size,
                              hipStream_t stream) {
  const int* y = (const int*)d_in[0];
  const int* x = (const int*)d_in[1];
  const float* cam = (const float*)d_in[2];
  const float* table = (const float*)d_in[3];
  const float* W1 = (const float*)d_in[4];
  const float* b1 = (const float*)d_in[5];
  const float* W2 = (const float*)d_in[6];
  const float* b2 = (const float*)d_in[7];
  const float* W3 = (const float*)d_in[8];
  const float* b3 = (const float*)d_in[9];
  float* out = (float*)d_out;

  _Float16* Wh = (_Float16*)d_ws;      // W1h | W2h | W3h contiguous, 983040 B
  _Float16* W1h = Wh;                  // 512*64
  _Float16* W2h = W1h + 512 * 64;      // 512*512
  _Float16* W3h = W2h + 512 * 512;     // 384*512

  hg_cvt_all<<<480, 256, 0, stream>>>(W1, W2, W3, Wh);

  const int nblocks = (1 << 19) / 64;  // 8192
  hg_fused<<<nblocks, 512, 0, stream>>>(y, x, cam, table, W1h, b1, W2h, b2, W3h, b3, out);
}